// Round 9
// baseline (339.021 us; speedup 1.0000x reference)
//
#include <hip/hip_runtime.h>

#define BB 16      // batch
#define CC 64      // channels (Cin = Cout = 64)
#define HH 128
#define WW 128
#define MM 67      // modes per axis
#define MODES (MM*MM)   // 4489
#define MC 32      // mode chunk for mix
#define NCHUNK 141 // ceil(4489/32)

typedef float f4 __attribute__((ext_vector_type(4)));

#define AS1 __attribute__((address_space(1)))
#define AS3 __attribute__((address_space(3)))

__constant__ float DEC_LO[8] = {-0.010597401784997278f, 0.032883011666982945f, 0.030841381835986965f,
                                -0.18703481171888114f, -0.02798376941698385f, 0.6308807679295904f,
                                0.7148465705525415f, 0.23037781330885523f};
__constant__ float DEC_HI[8] = {-0.23037781330885523f, 0.7148465705525415f, -0.6308807679295904f,
                                -0.02798376941698385f, 0.18703481171888114f, 0.030841381835986965f,
                                -0.032883011666982945f, -0.010597401784997278f};

// ---------------- analysis along W: x (B,C,H,W) -> t1 (B,C,2,H,67) ----------------
__global__ __launch_bounds__(256) void dwt_w(const float* __restrict__ x, float* __restrict__ t1) {
    __shared__ float row[8][128];
    const int bc = blockIdx.x;           // 0..1023
    const int h0 = blockIdx.y * 8;       // 0..120
    const int t  = threadIdx.x;
    {
        int r = t >> 5, c = (t & 31) << 2;
        const float4 v = *(const float4*)&x[((size_t)bc * HH + h0 + r) * WW + c];
        row[r][c] = v.x; row[r][c+1] = v.y; row[r][c+2] = v.z; row[r][c+3] = v.w;
    }
    __syncthreads();
    for (int oidx = t; oidx < 8 * 2 * MM; oidx += 256) {
        int wo = oidx % MM;
        int f  = (oidx / MM) & 1;
        int r  = oidx / (2 * MM);
        const float* flt = f ? DEC_HI : DEC_LO;
        float acc = 0.f;
        int base = 2 * wo - 6;
        #pragma unroll
        for (int k = 0; k < 8; ++k) {
            int i = base + k;
            i = (i < 0) ? (-i - 1) : i;
            i = (i >= WW) ? (2 * WW - 1 - i) : i;
            acc += row[r][i] * flt[7 - k];
        }
        t1[(((size_t)bc * 2 + f) * HH + h0 + r) * MM + wo] = acc;
    }
}

// ---------------- analysis along H: t1 -> coeff (B,C,4,67,67), band = fw*2+fh ------
__global__ __launch_bounds__(256) void dwt_h(const float* __restrict__ t1, float* __restrict__ cf) {
    const int NH2 = (MM + 1) / 2;  // 34 ho-pairs
    int idx = blockIdx.x * 256 + threadIdx.x;
    const int N = BB * CC * 2 * NH2 * MM;
    if (idx >= N) return;
    int wo = idx % MM;
    int hp = (idx / MM) % NH2;
    int fw = (idx / (MM * NH2)) % 2;
    int bc = idx / (MM * NH2 * 2);
    const float* src = t1 + ((size_t)(bc * 2 + fw) * HH) * MM + wo;
    float rv[10];
    #pragma unroll
    for (int k = 0; k < 10; ++k) {
        int i = 4 * hp - 6 + k;
        i = (i < 0) ? (-i - 1) : i;
        i = (i >= HH) ? (2 * HH - 1 - i) : i;
        rv[k] = src[(size_t)i * MM];
    }
    float lo0 = 0.f, hi0 = 0.f, lo1 = 0.f, hi1 = 0.f;
    #pragma unroll
    for (int k = 0; k < 8; ++k) {
        lo0 += rv[k]     * DEC_LO[7 - k];
        hi0 += rv[k]     * DEC_HI[7 - k];
        lo1 += rv[k + 2] * DEC_LO[7 - k];
        hi1 += rv[k + 2] * DEC_HI[7 - k];
    }
    int ho0 = 2 * hp, ho1 = 2 * hp + 1;
    size_t b0 = (size_t)(bc * 4 + fw * 2 + 0) * MM;
    size_t b1 = (size_t)(bc * 4 + fw * 2 + 1) * MM;
    cf[(b0 + ho0) * MM + wo] = lo0;
    cf[(b1 + ho0) * MM + wo] = hi0;
    if (ho1 < MM) {
        cf[(b0 + ho1) * MM + wo] = lo1;
        cf[(b1 + ho1) * MM + wo] = hi1;
    }
}

// ---------------- per-mode channel mix ----------------
// out[b,o,band,m] = sum_i cf[b,i,band,m] * w_band[i,o,m]
// Block = (band, 32-mode chunk), ALL b / i / o => zero-redundancy HBM fetch.
// coeff tile (16b x 64i x 32m = 128 KB) in LDS.
// Weight chunk per i (64o x 32m = 8 KB) DMA'd into a 2-slot LDS ring via
// global_load_lds (size=4: rows are 4-mod-16-byte aligned) — the HBM/L3
// latency hides under the previous iteration's compute, independent of
// register allocation (round 8's register prefetch was serialized by the
// compiler: VGPR=88 < the 96 needed, VALUBusy 12.7%).
// Per thread per i: 4 weight ds_read_b128 + 4 coeff broadcast reads + 16 f4 FMA.
__global__ __launch_bounds__(512, 2) void mix_k(const float* __restrict__ cf,
                                                const float* __restrict__ w1,
                                                const float* __restrict__ w2,
                                                const float* __restrict__ w3,
                                                const float* __restrict__ w4,
                                                float* __restrict__ out) {
    __shared__ float sc[BB][CC][MC];   // coeff [b][i][m]  128 KB
    __shared__ float sw[2][CC][MC];    // weight ring [slot][o][m]  16 KB
    // --- bijective XCD swizzle over NWG = 141*4 = 564 = 8*70 + 4 ---
    int flat = blockIdx.y * NCHUNK + blockIdx.x;
    {
        const int q = 564 / 8, r = 564 % 8;          // 70, 4
        int xcd = flat & 7, j = flat >> 3;
        flat = (xcd < r ? xcd * (q + 1) : r * (q + 1) + (xcd - r) * q) + j;
    }
    const int band = flat / NCHUNK;
    const int m0   = min((flat % NCHUNK) * MC, MODES - MC);  // last chunks overlap (identical values)
    const int tid  = threadIdx.x;
    const int lane = tid & 63, wv = tid >> 6;
    const float* w = (band == 0) ? w1 : (band == 1) ? w2 : (band == 2) ? w3 : w4;

    const int wrow = wv << 3;   // this wave stages o-rows wrow..wrow+7

    // DMA one 8 KB weight chunk (cin = ii) into sw[slot]; 4 instrs/wave,
    // each instr: 64 lanes x 4 B = 256 B = 2 rows of 128 B.
    #define STAGE_W(slot, ii)                                                                \
    {                                                                                        \
        const float* _src = w + ((size_t)(ii) * CC + wrow) * MODES + m0;                     \
        _Pragma("unroll")                                                                    \
        for (int _q = 0; _q < 4; ++_q) {                                                     \
            __builtin_amdgcn_global_load_lds(                                                \
                (const AS1 void*)(_src + (size_t)(_q * 2 + (lane >> 5)) * MODES + (lane & 31)), \
                (AS3 void*)&sw[slot][wrow + _q * 2][0], 4, 0, 0);                            \
        }                                                                                    \
    }

    STAGE_W(0, 0);   // prologue DMA hides under coeff staging

    // ---- stage coeff tile: 1024 rows (b*64+i) x 32 floats, 512 threads ----
    {
        const int c = tid & 7, r0 = tid >> 3;        // 8 threads/row
        #pragma unroll
        for (int p = 0; p < 16; ++p) {
            int r = r0 + (p << 6);                   // 0..1023
            f4 v = *(const f4*)(cf + ((size_t)(r * 4) + band) * MODES + m0 + c * 4);
            *(f4*)&sc[r >> 6][r & 63][c * 4] = v;
        }
    }
    __syncthreads();   // drains coeff stores + wave's own STAGE_W(0) (vmcnt 0) + barrier

    const int b0   = (wv & 3) * 4;                      // wave's batch quad
    const int os   = (wv >> 2) * 32 + (lane >> 3) * 4;  // first of 4 consecutive o
    const int mc4f = (lane & 7) * 4;                    // float offset of this thread's 4 modes

    f4 acc[4][4];   // [b][o]
    #pragma unroll
    for (int j = 0; j < 4; ++j)
        #pragma unroll
        for (int k = 0; k < 4; ++k) acc[j][k] = (f4)(0.f);

    #pragma unroll 1
    for (int i = 0; i < CC; ++i) {
        if (i + 1 < CC) STAGE_W((i + 1) & 1, i + 1);

        const float (*swc)[MC] = (const float (*)[MC])sw[i & 1];
        f4 w0 = *(const f4*)&swc[os + 0][mc4f];
        f4 w1v = *(const f4*)&swc[os + 1][mc4f];
        f4 w2v = *(const f4*)&swc[os + 2][mc4f];
        f4 w3v = *(const f4*)&swc[os + 3][mc4f];
        f4 s0 = *(const f4*)&sc[b0 + 0][i][mc4f];
        f4 s1 = *(const f4*)&sc[b0 + 1][i][mc4f];
        f4 s2 = *(const f4*)&sc[b0 + 2][i][mc4f];
        f4 s3 = *(const f4*)&sc[b0 + 3][i][mc4f];
        acc[0][0] += s0 * w0;  acc[0][1] += s0 * w1v;  acc[0][2] += s0 * w2v;  acc[0][3] += s0 * w3v;
        acc[1][0] += s1 * w0;  acc[1][1] += s1 * w1v;  acc[1][2] += s1 * w2v;  acc[1][3] += s1 * w3v;
        acc[2][0] += s2 * w0;  acc[2][1] += s2 * w1v;  acc[2][2] += s2 * w2v;  acc[2][3] += s2 * w3v;
        acc[3][0] += s3 * w0;  acc[3][1] += s3 * w1v;  acc[3][2] += s3 * w2v;  acc[3][3] += s3 * w3v;

        __syncthreads();   // vmcnt(0): own DMA for i+1 landed; barrier: everyone's landed,
                           // and all reads of sw[i&1] are done before it's overwritten at i+2
    }

    #pragma unroll
    for (int j = 0; j < 4; ++j)
        #pragma unroll
        for (int k = 0; k < 4; ++k)
            *(f4*)&out[((size_t)(((b0 + j) * CC + os + k) * 4) + band) * MODES + m0 + mc4f] = acc[j][k];
    #undef STAGE_W
}

// ---------------- synthesis along H: mixed (B,C,4,67,67) -> u1 (B,C,2,128,67) ------
__global__ __launch_bounds__(256) void idwt_h(const float* __restrict__ mx, float* __restrict__ u1) {
    int idx = blockIdx.x * 256 + threadIdx.x;
    const int N = BB * CC * 2 * (HH / 2) * MM;
    if (idx >= N) return;
    int wo = idx % MM;
    int a  = (idx / MM) % (HH / 2);
    int fw = (idx / (MM * (HH / 2))) % 2;
    int bc = idx / (MM * (HH / 2) * 2);
    const float* lo = mx + ((size_t)(bc * 4 + fw * 2) * MODES) + wo;
    const float* hi = lo + MODES;
    float l[4], h4[4];
    #pragma unroll
    for (int q = 0; q < 4; ++q) {
        l[q]  = lo[(size_t)(a + q) * MM];
        h4[q] = hi[(size_t)(a + q) * MM];
    }
    float out0 = 0.f, out1 = 0.f;
    #pragma unroll
    for (int q = 0; q < 4; ++q) {
        out0 += l[q] * DEC_LO[2 * q + 1] + h4[q] * DEC_HI[2 * q + 1];  // h = 2a
        out1 += l[q] * DEC_LO[2 * q]     + h4[q] * DEC_HI[2 * q];      // h = 2a+1
    }
    size_t base = ((size_t)(bc * 2 + fw) * HH + 2 * a) * MM + wo;
    u1[base]      = out0;
    u1[base + MM] = out1;
}

// ---------------- synthesis along W: u1 -> out (B,C,128,128) ----------------
__global__ __launch_bounds__(256) void idwt_w(const float* __restrict__ u1, float* __restrict__ out) {
    int idx = blockIdx.x * 256 + threadIdx.x;
    const int N = BB * CC * HH * (WW / 2);
    if (idx >= N) return;
    int a  = idx % (WW / 2);
    int h  = (idx / (WW / 2)) % HH;
    int bc = idx / ((WW / 2) * HH);
    const float* lo = u1 + (size_t)(bc * 2) * HH * MM + (size_t)h * MM;
    const float* hi = lo + (size_t)HH * MM;
    float l[4], h4[4];
    #pragma unroll
    for (int q = 0; q < 4; ++q) {
        l[q]  = lo[a + q];
        h4[q] = hi[a + q];
    }
    float out0 = 0.f, out1 = 0.f;
    #pragma unroll
    for (int q = 0; q < 4; ++q) {
        out0 += l[q] * DEC_LO[2 * q + 1] + h4[q] * DEC_HI[2 * q + 1];  // n = 2a
        out1 += l[q] * DEC_LO[2 * q]     + h4[q] * DEC_HI[2 * q];      // n = 2a+1
    }
    float2 r = make_float2(out0, out1);
    *(float2*)&out[((size_t)bc * HH + h) * WW + 2 * a] = r;
}

extern "C" void kernel_launch(void* const* d_in, const int* in_sizes, int n_in,
                              void* d_out, int out_size, void* d_ws, size_t ws_size,
                              hipStream_t stream) {
    const float* x  = (const float*)d_in[0];
    const float* w1 = (const float*)d_in[1];
    const float* w2 = (const float*)d_in[2];
    const float* w3 = (const float*)d_in[3];
    const float* w4 = (const float*)d_in[4];
    float* out = (float*)d_out;

    const size_t COEFF_FLTS = (size_t)BB * CC * 4 * MODES;
    float* buf1 = (float*)d_ws;
    float* buf2 = buf1 + COEFF_FLTS;

    // 1) DWT along W: x -> buf1 (t1)
    {
        dim3 grid(BB * CC, HH / 8);
        dwt_w<<<grid, 256, 0, stream>>>(x, buf1);
    }
    // 2) DWT along H: buf1 -> buf2 (coeff)
    {
        int N = BB * CC * 2 * ((MM + 1) / 2) * MM;
        dwt_h<<<(N + 255) / 256, 256, 0, stream>>>(buf1, buf2);
    }
    // 3) per-mode channel mixing: buf2 -> buf1 (mixed)
    {
        dim3 grid(NCHUNK, 4);   // (141 mode-chunks, 4 bands)
        mix_k<<<grid, 512, 0, stream>>>(buf2, w1, w2, w3, w4, buf1);
    }
    // 4) inverse DWT along H: buf1 -> buf2 (u1)
    {
        int N = BB * CC * 2 * (HH / 2) * MM;
        idwt_h<<<(N + 255) / 256, 256, 0, stream>>>(buf1, buf2);
    }
    // 5) inverse DWT along W: buf2 -> d_out
    {
        int N = BB * CC * HH * (WW / 2);
        idwt_w<<<(N + 255) / 256, 256, 0, stream>>>(buf2, out);
    }
}